// Round 19
// baseline (32.150 us; speedup 1.0000x reference)
//
#include <hip/hip_runtime.h>
#include <hip/hip_bf16.h>

// AWQ 4-bit linear: out[32,11008] = x[32,4096] @ ((q - z)*s) + bias
// Round 19: BLOCK-COUNT HALVING test of the dispatch-rate model
// (ledger fit: wall_main ~= N_blocks * ~25ns + tail; R12 5504->146us,
// R10 1376->36us, R18 688->22us). 512-thread blocks: waves 0-3 run
// kchunk 2*kc2, waves 4-7 run kchunk 2*kc2+1 (each wave: 64 cols x 256 k,
// program byte-identical to R18's verified loop). NBLK 688 -> 344 = 8*43.
// LDS 64KB/block -> 2 blocks/CU cap >= 1.34 demand; waves/CU 10.75 as
// before. bf16 slabs + separate reduce (R17 lesson: no intra-kernel
// cross-XCD reduction), non-temporal slab traffic, inline A-conversion.

#define IN_F   4096
#define OUT_F  11008
#define WCOLS  1376
#define NCOLB  43                 // 256-col regions
#define KSPLIT 16
#define CHUNK  (IN_F/KSPLIT)      // 256
#define NTILE  (CHUNK/32)         // 8
#define NBLK   (NCOLB*8)          // 344 = 8*43 (2 kchunks per block)
#define MROWS  32
#define SLAB   (MROWS*OUT_F)      // elements per k-partial slab (352256)

typedef __attribute__((ext_vector_type(8))) short  short8;
typedef __attribute__((ext_vector_type(4))) unsigned short ushort4v;
typedef __attribute__((ext_vector_type(4))) float  f32x4;
typedef __attribute__((ext_vector_type(4))) int    int4v;

__device__ __forceinline__ short f2bf(float f) {
  return (short)__builtin_bit_cast(unsigned short, (__bf16)f);
}
__device__ __forceinline__ unsigned short f2bfu(float f) {
  return __builtin_bit_cast(unsigned short, (__bf16)f);
}
__device__ __forceinline__ float bf2f(unsigned short u) {
  return __builtin_bit_cast(float, ((unsigned int)u) << 16);
}
__device__ __forceinline__ f32x4 mfma16(short8 a, short8 b, f32x4 c) {
  return __builtin_amdgcn_mfma_f32_16x16x32_bf16(a, b, c, 0, 0, 0);
}

__global__ void awq_init(const float* __restrict__ bias, float* __restrict__ out) {
  int o = blockIdx.x * 256 + threadIdx.x;
  out[blockIdx.y * OUT_F + o] = bias[o];
}

__global__ __launch_bounds__(256) void awq_reduce(
    const unsigned short* __restrict__ ws, const float* __restrict__ bias,
    float* __restrict__ out)
{
  const int i = blockIdx.x * 256 + threadIdx.x;    // 4-col id, 88064 total
  f32x4 s = *(const f32x4*)(bias + (i % (OUT_F / 4)) * 4);
  const ushort4v* w4 = (const ushort4v*)ws;
  #pragma unroll
  for (int k = 0; k < KSPLIT; ++k) {
    ushort4v v = __builtin_nontemporal_load(&w4[k * (SLAB / 4) + i]);
    #pragma unroll
    for (int j = 0; j < 4; ++j) s[j] += bf2f(v[j]);
  }
  ((f32x4*)out)[i] = s;
}

template<bool TOWS>
__global__ __launch_bounds__(512, 2) void awq_main(
    const float* __restrict__ x,
    const int* __restrict__ qw, const int* __restrict__ qz,
    const float* __restrict__ sc, void* __restrict__ outp)
{
  // Per-wave, per-half private staging: [buf][wave8][half][512 dw] = 64 KB.
  __shared__ int lds[2][8][2][512];

  const int tid  = threadIdx.x;
  const int w8   = tid >> 6;           // wave 0..7
  const int wk   = w8 & 3;             // 64-col stripe within region
  const int lane = tid & 63;
  const int q4   = lane >> 4;          // MFMA k-octet
  const int cl   = lane & 15;          // MFMA col-in-frag
  const int ww   = lane & 3;           // dequant: word -> cols 8ww..8ww+7
  const int kp2  = lane >> 2;          // dequant: k-pair 0..15
  const int kps  = kp2 ^ (ww << 2);    // swizzled k-pair slot (verified)

  // Bijective XCD swizzle (344 = 8*43)
  const int b  = blockIdx.x;
  const int L  = (b & 7) * (NBLK / 8) + (b >> 3);
  const int colb = L % NCOLB;
  const int kc2  = L / NCOLB;          // 0..7
  const int kchunk = kc2 * 2 + (w8 >> 2);   // waves 0-3: even, 4-7: odd

  const int cb  = colb * 256;          // first output column of region
  const int wcb = colb * 32;           // first packed word of region
  const int K0  = kchunk * CHUNK;
  const int g0  = kchunk * (CHUNK / 128);   // 2 groups per chunk
  const int cw  = cb + wk * 64;        // wave's first column
  const int wqw = wcb + wk * 8;        // wave's first packed word

  // group scale/zero per half: raw staging -> converted s8/zs8
  f32x4 sra[2], srb[2]; int zrw[2];
  float s8[2][8], zs8[2][8];
  auto load_group_raw = [&](int g) {
    #pragma unroll
    for (int h = 0; h < 2; ++h) {
      sra[h] = *(const f32x4*)(sc + g * OUT_F + cw + h * 32 + ww * 8);
      srb[h] = *(const f32x4*)(sc + g * OUT_F + cw + h * 32 + ww * 8 + 4);
      zrw[h] = qz[g * WCOLS + wqw + h * 4 + ww];
    }
  };
  auto conv_group = [&]() {
    #pragma unroll
    for (int h = 0; h < 2; ++h) {
      #pragma unroll
      for (int j = 0; j < 8; ++j) {
        const int sh = 4 * (j >> 1) + 16 * (j & 1);   // shift = 4*REV[j]
        const float sv = (j < 4) ? sra[h][j] : srb[h][j - 4];
        s8[h][j]  = sv;
        zs8[h][j] = -(float)((zrw[h] >> sh) & 15) * sv;
      }
    }
  };
  auto load_a = [&](int t, int mf) -> short8 {
    const int m = cl + 16 * mf;
    const int k = K0 + t * 32 + q4 * 8;
    const f32x4* xp = (const f32x4*)(x + m * IN_F + k);
    f32x4 lo = xp[0], hi = xp[1];
    short8 af;
    #pragma unroll
    for (int j = 0; j < 4; ++j) { af[j] = f2bf(lo[j]); af[4 + j] = f2bf(hi[j]); }
    return af;
  };
  // read (col c, kp=4q4+i) stored at c*16 + (kp ^ ((c>>3)<<2)):
  // b128 at c*16 + 4*(q4 ^ ((c>>3)&3)) -> k-contiguous 8q4..8q4+7.
  auto read_b = [&](int p, int h, int c) -> short8 {
    const int idx = c * 16 + 4 * (q4 ^ ((c >> 3) & 3));
    return __builtin_bit_cast(short8, *(const int4v*)&lds[p][w8][h][idx]);
  };

  // ---- prologue: group-0 raws, ALL q-loads (8 tiles x 2 halves) to regs.
  load_group_raw(g0);
  int qa[NTILE][2], qb[NTILE][2];
  #pragma unroll
  for (int t = 0; t < NTILE; ++t) {
    #pragma unroll
    for (int h = 0; h < 2; ++h) {
      const int r = (K0 + t * 32 + 2 * kp2) * WCOLS + wqw + h * 4 + ww;
      qa[t][h] = qw[r];
      qb[t][h] = qw[r + WCOLS];
    }
  }
  conv_group();
  f32x4 acc[2][2][2] = {};   // [mf][h][cfrag]

  #pragma unroll
  for (int t = 0; t < NTILE; ++t) {
    // only in-loop VMEM: L2/L3-hot a-loads, shared by both halves
    short8 a0 = load_a(t, 0), a1 = load_a(t, 1);
    if (t == 2) load_group_raw(g0 + 1);   // 2 tiles early, drained once
    if (t == 4) conv_group();             // group 1 live for tiles 4..7

    const int p = t & 1;
    // two independent dequant->LDS streams (h=0,1)
    #pragma unroll
    for (int h = 0; h < 2; ++h) {
      #pragma unroll
      for (int j = 0; j < 8; ++j) {
        const int sh = 4 * (j >> 1) + 16 * (j & 1);
        const float lo = fmaf((float)((qa[t][h] >> sh) & 15), s8[h][j], zs8[h][j]);
        const float hi = fmaf((float)((qb[t][h] >> sh) & 15), s8[h][j], zs8[h][j]);
        const unsigned int pk =
            (unsigned int)(unsigned short)f2bf(lo) |
            ((unsigned int)(unsigned short)f2bf(hi) << 16);
        lds[p][w8][h][(ww * 8 + j) * 16 + kps] = (int)pk;
      }
    }
    // no barrier: same-wave ds_write -> ds_read via lgkmcnt only

    #pragma unroll
    for (int h = 0; h < 2; ++h) {
      short8 bf0 = read_b(p, h, cl);
      short8 bf1 = read_b(p, h, cl + 16);
      acc[0][h][0] = mfma16(a0, bf0, acc[0][h][0]);
      acc[0][h][1] = mfma16(a0, bf1, acc[0][h][1]);
      acc[1][h][0] = mfma16(a1, bf0, acc[1][h][0]);
      acc[1][h][1] = mfma16(a1, bf1, acc[1][h][1]);
    }
  }

  // ---- epilogue
  const int r0 = q4 * 4;
  if constexpr (TOWS) {
    // bf16 partials, non-temporal (write-once-read-once; skip L2)
    unsigned short* wsp = (unsigned short*)outp + kchunk * SLAB;
    #pragma unroll
    for (int mf = 0; mf < 2; ++mf) {
      #pragma unroll
      for (int h = 0; h < 2; ++h) {
        #pragma unroll
        for (int i = 0; i < 4; ++i) {
          const int row = mf * 16 + r0 + i;
          const int c0  = cw + h * 32 + cl;
          __builtin_nontemporal_store(f2bfu(acc[mf][h][0][i]),
                                      wsp + row * OUT_F + c0);
          __builtin_nontemporal_store(f2bfu(acc[mf][h][1][i]),
                                      wsp + row * OUT_F + c0 + 16);
        }
      }
    }
  } else {
    // fallback: fp32 atomics onto bias-initialized out
    float* op = (float*)outp;
    #pragma unroll
    for (int mf = 0; mf < 2; ++mf) {
      #pragma unroll
      for (int h = 0; h < 2; ++h) {
        #pragma unroll
        for (int i = 0; i < 4; ++i) {
          const int row = mf * 16 + r0 + i;
          const int c0  = cw + h * 32 + cl;
          atomicAdd(op + row * OUT_F + c0,      acc[mf][h][0][i]);
          atomicAdd(op + row * OUT_F + c0 + 16, acc[mf][h][1][i]);
        }
      }
    }
  }
}

extern "C" void kernel_launch(void* const* d_in, const int* in_sizes, int n_in,
                              void* d_out, int out_size, void* d_ws, size_t ws_size,
                              hipStream_t stream) {
  const float* x    = (const float*)d_in[0];
  const int*   qwp  = (const int*)d_in[1];
  const int*   qzp  = (const int*)d_in[2];
  const float* scp  = (const float*)d_in[3];
  const float* bias = (const float*)d_in[4];
  float* out = (float*)d_out;

  const size_t ws_slabs = (size_t)KSPLIT * SLAB * 2;   // 11.25 MB (bf16)

  if (ws_size >= ws_slabs) {
    unsigned short* ws = (unsigned short*)d_ws;
    awq_main<true><<<NBLK, 512, 0, stream>>>(x, qwp, qzp, scp, ws);
    awq_reduce<<<SLAB / 4 / 256, 256, 0, stream>>>(ws, bias, out);
  } else {
    awq_init<<<dim3(43, 32), 256, 0, stream>>>(bias, out);
    awq_main<false><<<NBLK, 512, 0, stream>>>(x, qwp, qzp, scp, out);
  }
}

// Round 20
// 26.390 us; speedup vs baseline: 1.2183x; 1.2183x over previous
//
#include <hip/hip_runtime.h>
#include <hip/hip_bf16.h>

// AWQ 4-bit linear: out[32,11008] = x[32,4096] @ ((q - z)*s) + bias
// Round 20: R18 winner (27.6us; 688 blk x 4 fat waves, 2 ILP streams,
// q-hoist, per-wave swizzled LDS, barrier-free, bf16 nt-slabs + reduce)
// + per-tile stall killers, structure-preserving:
//  1) LDS software pipeline: iteration t = {read frags(t-1), prefetch a(t),
//     dequant+write(t), mfma(t-1)} -> ~240cy LDS round-trip hidden under
//     dequant VALU instead of exposed 8x per wave.
//  2) A-prefetch one iteration ahead (named regs) -> MFMA never waits VMEM.
// Ledger: R19 refuted dispatch-rate model (344 blk -> 1.34 blk/CU ragged,
// Occ 15%, 43us); R13+R19 => time*occupancy ~ const, stalls convoy; only
// per-wave-stall reduction (R16) ever paid on main.

#define IN_F   4096
#define OUT_F  11008
#define WCOLS  1376
#define NCOLB  43                 // 256-col regions
#define KSPLIT 16
#define CHUNK  (IN_F/KSPLIT)      // 256
#define NTILE  (CHUNK/32)         // 8
#define NBLK   (NCOLB*KSPLIT)     // 688 = 8*86
#define MROWS  32
#define SLAB   (MROWS*OUT_F)      // elements per k-partial slab (352256)

typedef __attribute__((ext_vector_type(8))) short  short8;
typedef __attribute__((ext_vector_type(4))) unsigned short ushort4v;
typedef __attribute__((ext_vector_type(4))) float  f32x4;
typedef __attribute__((ext_vector_type(4))) int    int4v;

__device__ __forceinline__ short f2bf(float f) {
  return (short)__builtin_bit_cast(unsigned short, (__bf16)f);
}
__device__ __forceinline__ unsigned short f2bfu(float f) {
  return __builtin_bit_cast(unsigned short, (__bf16)f);
}
__device__ __forceinline__ float bf2f(unsigned short u) {
  return __builtin_bit_cast(float, ((unsigned int)u) << 16);
}
__device__ __forceinline__ f32x4 mfma16(short8 a, short8 b, f32x4 c) {
  return __builtin_amdgcn_mfma_f32_16x16x32_bf16(a, b, c, 0, 0, 0);
}

__global__ void awq_init(const float* __restrict__ bias, float* __restrict__ out) {
  int o = blockIdx.x * 256 + threadIdx.x;
  out[blockIdx.y * OUT_F + o] = bias[o];
}

__global__ __launch_bounds__(256) void awq_reduce(
    const unsigned short* __restrict__ ws, const float* __restrict__ bias,
    float* __restrict__ out)
{
  const int i = blockIdx.x * 256 + threadIdx.x;    // 4-col id, 88064 total
  f32x4 s = *(const f32x4*)(bias + (i % (OUT_F / 4)) * 4);
  const ushort4v* w4 = (const ushort4v*)ws;
  #pragma unroll
  for (int k = 0; k < KSPLIT; ++k) {
    ushort4v v = __builtin_nontemporal_load(&w4[k * (SLAB / 4) + i]);
    #pragma unroll
    for (int j = 0; j < 4; ++j) s[j] += bf2f(v[j]);
  }
  ((f32x4*)out)[i] = s;
}

template<bool TOWS>
__global__ __launch_bounds__(256, 3) void awq_main(
    const float* __restrict__ x,
    const int* __restrict__ qw, const int* __restrict__ qz,
    const float* __restrict__ sc, void* __restrict__ outp)
{
  // Per-wave, per-half private staging: [buf][wave][half][512 dw] = 32 KB.
  __shared__ int lds[2][4][2][512];

  const int tid  = threadIdx.x;
  const int w    = tid >> 6;           // wave 0..3 -> 64-col stripe
  const int lane = tid & 63;
  const int q4   = lane >> 4;          // MFMA k-octet
  const int cl   = lane & 15;          // MFMA col-in-frag
  const int ww   = lane & 3;           // dequant: word -> cols 8ww..8ww+7
  const int kp2  = lane >> 2;          // dequant: k-pair 0..15
  const int kps  = kp2 ^ (ww << 2);    // swizzled k-pair slot (verified)

  // Bijective XCD swizzle (688 = 8*86)
  const int b  = blockIdx.x;
  const int L  = (b & 7) * (NBLK / 8) + (b >> 3);
  const int colb   = L % NCOLB;
  const int kchunk = L / NCOLB;

  const int cb  = colb * 256;          // first output column of region
  const int wcb = colb * 32;           // first packed word of region
  const int K0  = kchunk * CHUNK;
  const int g0  = kchunk * (CHUNK / 128);   // 2 groups per chunk
  const int cw  = cb + w * 64;         // wave's first column
  const int wqw = wcb + w * 8;         // wave's first packed word

  // group scale/zero per half: raw staging -> converted s8/zs8
  f32x4 sra[2], srb[2]; int zrw[2];
  float s8[2][8], zs8[2][8];
  auto load_group_raw = [&](int g) {
    #pragma unroll
    for (int h = 0; h < 2; ++h) {
      sra[h] = *(const f32x4*)(sc + g * OUT_F + cw + h * 32 + ww * 8);
      srb[h] = *(const f32x4*)(sc + g * OUT_F + cw + h * 32 + ww * 8 + 4);
      zrw[h] = qz[g * WCOLS + wqw + h * 4 + ww];
    }
  };
  auto conv_group = [&]() {
    #pragma unroll
    for (int h = 0; h < 2; ++h) {
      #pragma unroll
      for (int j = 0; j < 8; ++j) {
        const int sh = 4 * (j >> 1) + 16 * (j & 1);   // shift = 4*REV[j]
        const float sv = (j < 4) ? sra[h][j] : srb[h][j - 4];
        s8[h][j]  = sv;
        zs8[h][j] = -(float)((zrw[h] >> sh) & 15) * sv;
      }
    }
  };
  auto load_a = [&](int t, int mf) -> short8 {
    const int m = cl + 16 * mf;
    const int k = K0 + t * 32 + q4 * 8;
    const f32x4* xp = (const f32x4*)(x + m * IN_F + k);
    f32x4 lo = xp[0], hi = xp[1];
    short8 af;
    #pragma unroll
    for (int j = 0; j < 4; ++j) { af[j] = f2bf(lo[j]); af[4 + j] = f2bf(hi[j]); }
    return af;
  };
  // read (col c, kp=4q4+i) stored at c*16 + (kp ^ ((c>>3)<<2)):
  // b128 at c*16 + 4*(q4 ^ ((c>>3)&3)) -> k-contiguous 8q4..8q4+7.
  auto read_b = [&](int p, int h, int c) -> short8 {
    const int idx = c * 16 + 4 * (q4 ^ ((c >> 3) & 3));
    return __builtin_bit_cast(short8, *(const int4v*)&lds[p][w][h][idx]);
  };

  // ---- prologue: group-0 raws, ALL q-loads (8 tiles x 2 halves) to regs.
  load_group_raw(g0);
  int qa[NTILE][2], qb[NTILE][2];
  #pragma unroll
  for (int t = 0; t < NTILE; ++t) {
    #pragma unroll
    for (int h = 0; h < 2; ++h) {
      const int r = (K0 + t * 32 + 2 * kp2) * WCOLS + wqw + h * 4 + ww;
      qa[t][h] = qw[r];
      qb[t][h] = qw[r + WCOLS];
    }
  }
  conv_group();
  f32x4 acc[2][2][2] = {};   // [mf][h][cfrag]

  // dequant + LDS-write for tile t (p = t&1 static under full unroll)
  auto dq_write = [&](int t) {
    const int p = t & 1;
    #pragma unroll
    for (int h = 0; h < 2; ++h) {
      #pragma unroll
      for (int j = 0; j < 8; ++j) {
        const int sh = 4 * (j >> 1) + 16 * (j & 1);
        const float lo = fmaf((float)((qa[t][h] >> sh) & 15), s8[h][j], zs8[h][j]);
        const float hi = fmaf((float)((qb[t][h] >> sh) & 15), s8[h][j], zs8[h][j]);
        const unsigned int pk =
            (unsigned int)(unsigned short)f2bf(lo) |
            ((unsigned int)(unsigned short)f2bf(hi) << 16);
        lds[p][w][h][(ww * 8 + j) * 16 + kps] = (int)pk;
      }
    }
  };

  // ---- pipelined main loop: write(t) while consuming (t-1)
  dq_write(0);
  short8 a0c = load_a(0, 0), a1c = load_a(0, 1);

  #pragma unroll
  for (int t = 1; t < NTILE; ++t) {
    const int pm = (t - 1) & 1;
    // reads for tile t-1 (writes(t-1) landed during prior iteration)
    short8 bf00 = read_b(pm, 0, cl), bf01 = read_b(pm, 0, cl + 16);
    short8 bf10 = read_b(pm, 1, cl), bf11 = read_b(pm, 1, cl + 16);
    // prefetch a(t) one iteration ahead
    short8 a0n = load_a(t, 0), a1n = load_a(t, 1);
    if (t == 2) load_group_raw(g0 + 1);   // raws 2 tiles early
    if (t == 4) conv_group();             // group 1 live for tiles 4..7

    dq_write(t);                          // VALU hides the reads above

    acc[0][0][0] = mfma16(a0c, bf00, acc[0][0][0]);
    acc[0][0][1] = mfma16(a0c, bf01, acc[0][0][1]);
    acc[1][0][0] = mfma16(a1c, bf00, acc[1][0][0]);
    acc[1][0][1] = mfma16(a1c, bf01, acc[1][0][1]);
    acc[0][1][0] = mfma16(a0c, bf10, acc[0][1][0]);
    acc[0][1][1] = mfma16(a0c, bf11, acc[0][1][1]);
    acc[1][1][0] = mfma16(a1c, bf10, acc[1][1][0]);
    acc[1][1][1] = mfma16(a1c, bf11, acc[1][1][1]);

    a0c = a0n; a1c = a1n;
  }

  // ---- epilogue tile NTILE-1
  {
    const int pm = (NTILE - 1) & 1;
    short8 bf00 = read_b(pm, 0, cl), bf01 = read_b(pm, 0, cl + 16);
    short8 bf10 = read_b(pm, 1, cl), bf11 = read_b(pm, 1, cl + 16);
    acc[0][0][0] = mfma16(a0c, bf00, acc[0][0][0]);
    acc[0][0][1] = mfma16(a0c, bf01, acc[0][0][1]);
    acc[1][0][0] = mfma16(a1c, bf00, acc[1][0][0]);
    acc[1][0][1] = mfma16(a1c, bf01, acc[1][0][1]);
    acc[0][1][0] = mfma16(a0c, bf10, acc[0][1][0]);
    acc[0][1][1] = mfma16(a0c, bf11, acc[0][1][1]);
    acc[1][1][0] = mfma16(a1c, bf10, acc[1][1][0]);
    acc[1][1][1] = mfma16(a1c, bf11, acc[1][1][1]);
  }

  // ---- output epilogue
  const int r0 = q4 * 4;
  if constexpr (TOWS) {
    // bf16 partials, non-temporal (write-once-read-once; skip L2)
    unsigned short* wsp = (unsigned short*)outp + kchunk * SLAB;
    #pragma unroll
    for (int mf = 0; mf < 2; ++mf) {
      #pragma unroll
      for (int h = 0; h < 2; ++h) {
        #pragma unroll
        for (int i = 0; i < 4; ++i) {
          const int row = mf * 16 + r0 + i;
          const int c0  = cw + h * 32 + cl;
          __builtin_nontemporal_store(f2bfu(acc[mf][h][0][i]),
                                      wsp + row * OUT_F + c0);
          __builtin_nontemporal_store(f2bfu(acc[mf][h][1][i]),
                                      wsp + row * OUT_F + c0 + 16);
        }
      }
    }
  } else {
    // fallback: fp32 atomics onto bias-initialized out
    float* op = (float*)outp;
    #pragma unroll
    for (int mf = 0; mf < 2; ++mf) {
      #pragma unroll
      for (int h = 0; h < 2; ++h) {
        #pragma unroll
        for (int i = 0; i < 4; ++i) {
          const int row = mf * 16 + r0 + i;
          const int c0  = cw + h * 32 + cl;
          atomicAdd(op + row * OUT_F + c0,      acc[mf][h][0][i]);
          atomicAdd(op + row * OUT_F + c0 + 16, acc[mf][h][1][i]);
        }
      }
    }
  }
}

extern "C" void kernel_launch(void* const* d_in, const int* in_sizes, int n_in,
                              void* d_out, int out_size, void* d_ws, size_t ws_size,
                              hipStream_t stream) {
  const float* x    = (const float*)d_in[0];
  const int*   qwp  = (const int*)d_in[1];
  const int*   qzp  = (const int*)d_in[2];
  const float* scp  = (const float*)d_in[3];
  const float* bias = (const float*)d_in[4];
  float* out = (float*)d_out;

  const size_t ws_slabs = (size_t)KSPLIT * SLAB * 2;   // 11.25 MB (bf16)

  if (ws_size >= ws_slabs) {
    unsigned short* ws = (unsigned short*)d_ws;
    awq_main<true><<<NBLK, 256, 0, stream>>>(x, qwp, qzp, scp, ws);
    awq_reduce<<<SLAB / 4 / 256, 256, 0, stream>>>(ws, bias, out);
  } else {
    awq_init<<<dim3(43, 32), 256, 0, stream>>>(bias, out);
    awq_main<false><<<NBLK, 256, 0, stream>>>(x, qwp, qzp, scp, out);
  }
}